// Round 5
// baseline (98.609 us; speedup 1.0000x reference)
//
#include <hip/hip_runtime.h>
#include <cstdint>
#include <cstddef>

// ---------------- problem constants ----------------
#define NB    32          // batch
#define CI    128         // in channels
#define CO    256         // out channels
#define HW_   56          // spatial
#define HP    58          // padded spatial
#define KTOT  1152        // 128*9 reduction
#define NKT   36          // K-tiles of 32
#define MTOT  (NB * HW_ * HW_)   // 100352 output pixels

static constexpr size_t XP_ELEMS = (size_t)NB * HP * HP * CI;   // 13,776,896
static constexpr size_t WT_ELEMS = (size_t)CO * KTOT;           // 294,912
static constexpr size_t XP_BYTES = XP_ELEMS * 2;
static constexpr size_t WT_BYTES = WT_ELEMS * 2;

typedef __attribute__((ext_vector_type(8))) short bf16x8;
typedef __attribute__((ext_vector_type(4))) float f32x4;

__device__ __forceinline__ short f32_to_bf16(float f) {
  uint32_t u = __float_as_uint(f);
  uint32_t r = (u + 0x7FFFu + ((u >> 16) & 1u)) >> 16;
  return (short)r;
}

typedef __attribute__((address_space(3))) void       lds_void;
typedef const __attribute__((address_space(1))) void gbl_void;

__device__ __forceinline__ void gload16(const void* g, void* l) {
  // dest = wave-uniform LDS base; HW writes lane's 16B at base + lane*16
  __builtin_amdgcn_global_load_lds((gbl_void*)g, (lds_void*)l, 16, 0, 0);
}

// ---- pre-pass: x NCHW f32 -> padded NHWC bf16; wt OIHW -> [o][kh][kw][c] bf16 ----
__global__ void pad_convert(const float* __restrict__ x, short* __restrict__ xp,
                            const float* __restrict__ wt, short* __restrict__ wbT) {
  __shared__ float lds[CI][57];
  const int blk = blockIdx.x;    // NB*HP = 1856
  const int hp  = blk % HP;
  const int nb  = blk / HP;
  const int tid = threadIdx.x;   // 256

  // fold weight conversion into the first 1152 blocks (1152*256 == WT_ELEMS)
  if (blk < 1152) {
    int idx = blk * 256 + tid;
    int c  = idx & 127;
    int t  = idx >> 7;          // o*9 + kh*3 + kw
    int kw = t % 3;  int t2 = t / 3;
    int kh = t2 % 3; int o  = t2 / 3;
    wbT[idx] = f32_to_bf16(wt[(((size_t)o * CI + c) * 3 + kh) * 3 + kw]);
  }

  const bool interior = (hp >= 1 && hp <= HW_);
  if (interior) {
    const float* src = x + (size_t)nb * CI * HW_ * HW_ + (size_t)(hp - 1) * HW_;
    for (int t = tid; t < CI * HW_; t += 256) {
      int c = t / HW_, w = t - (t / HW_) * HW_;
      lds[c][w] = src[(size_t)c * HW_ * HW_ + w];
    }
  }
  __syncthreads();
  // vectorized store side: short4 per item (G13)
  short* dst = xp + (size_t)(nb * HP + hp) * HP * CI;
  for (int t = tid; t < HP * CI / 4; t += 256) {
    const int wp = t >> 5;          // 32 channel-quads per wp
    const int c4 = (t & 31) * 4;
    short4 s;
    if (interior && wp >= 1 && wp <= HW_) {
      s.x = f32_to_bf16(lds[c4 + 0][wp - 1]);
      s.y = f32_to_bf16(lds[c4 + 1][wp - 1]);
      s.z = f32_to_bf16(lds[c4 + 2][wp - 1]);
      s.w = f32_to_bf16(lds[c4 + 3][wp - 1]);
    } else {
      s.x = s.y = s.z = s.w = 0;
    }
    *(short4*)(dst + t * 4) = s;
  }
}

// scalar byte offset into an xp pixel row for K-tile u (tap + channel-quarter)
__device__ __forceinline__ int stage_aoff(int u) {
  const int tap = u >> 2;            // 0..8
  const int cq  = u & 3;             // channel quarter (32 ch)
  const int kh  = tap / 3, kw = tap - kh * 3;
  return ((kh * HP + kw) * CI + cq * 32) * 2;
}

// ---------------- main: implicit GEMM, 256x256 tile, BK=32, 8 waves ----------------
// m201-style rhythm: 2 phases/K-tile, 16 MFMA/phase, 2 barriers/phase
// (reads+stage -> barrier -> lgkmcnt(0)+sched_barrier -> setprio MFMA -> barrier).
// 3 LDS buffers x 32KB (A 256x32 + B 256x32 bf16) = 96KB -> 1 block/CU, 8 waves.
// Stage-ahead 2 K-tiles (A halves in phase A, B halves in phase B); vmcnt(4) at
// tile end confirms exactly tile v+1's 4 gloads; vmcnt(0) only at v=NKT-2.
// Swizzle (verified 0 conflicts R3/R4): LDS 16B-piece p holds global piece
// p ^ ((row>>1)&3); pre-swizzled gload source + swizzled ds_read (rule #21).
__global__ __launch_bounds__(512, 2) void conv_gemm(
    const short* __restrict__ xp, const short* __restrict__ wbT,
    const float* __restrict__ bias, float* __restrict__ out) {
  __shared__ __align__(16) char lds_[3 * 32768];

  const int tid = threadIdx.x;     // 512
  const int l   = tid & 63;
  const int wv  = tid >> 6;        // 0..7
  const int wm  = wv >> 2;         // 0..1  (m half: 128 rows)
  const int wn  = wv & 3;          // 0..3  (oc quarter: 64 cols)

  // grid 392 = 8 XCDs x 49; bijective chunked swizzle
  const int bid = blockIdx.x;
  const int mt  = (bid & 7) * 49 + (bid >> 3);

  // ---- staging source pointers (pre-swizzled per rule #21) ----
  // each gload: thread t writes LDS piece t (row = t>>2, piece = t&3);
  // source must hold piece (t&3) ^ ((row>>1)&3) = (t&3) ^ ((t>>3)&3)
  const int pcs  = (((tid & 3) ^ ((tid >> 3) & 3)) << 4);
  const int srow = tid >> 2;                  // 0..127
  const char *aSrc0, *aSrc1;
  {
#pragma unroll
    for (int q = 0; q < 2; ++q) {
      int m  = mt * 256 + 128 * q + srow;
      int nb = m / 3136, hw = m - nb * 3136;
      int h = hw / HW_, w = hw - (hw / HW_) * HW_;
      const char* p = (const char*)xp + ((size_t)((nb * HP + h) * HP + w) * CI) * 2 + pcs;
      if (q == 0) aSrc0 = p; else aSrc1 = p;
    }
  }
  const char* bSrc0 = (const char*)wbT + (size_t)(      srow) * KTOT * 2 + pcs;
  const char* bSrc1 = (const char*)wbT + (size_t)(128 + srow) * KTOT * 2 + pcs;

  // ---- frag read lane offsets (swizzled koff; dep only on lane, verified) ----
  const int lm   = l & 15;
  const int koff = (((l >> 4) ^ ((l >> 1) & 3)) << 4);
  const int raOff = (wm * 128 + lm) * 64 + koff;   // + g*1024 (g=0..7)
  const int rbOff = (wn * 64 + lm) * 64 + koff;    // + h*1024 (B region +16384)

  char* B0 = lds_;
  char* B1 = lds_ + 32768;
  char* B2 = lds_ + 65536;

#define STAGE_A(U, BUF)                                                      \
  {                                                                          \
    const int ao_ = stage_aoff(U);                                           \
    gload16(aSrc0 + ao_, (BUF) +        wv * 1024);                          \
    gload16(aSrc1 + ao_, (BUF) + 8192 + wv * 1024);                          \
  }
#define STAGE_B(U, BUF)                                                      \
  {                                                                          \
    const int bo_ = (U) * 64;                                                \
    gload16(bSrc0 + bo_, (BUF) + 16384 + wv * 1024);                         \
    gload16(bSrc1 + bo_, (BUF) + 24576 + wv * 1024);                         \
  }

  f32x4 acc[8][4];
#pragma unroll
  for (int g = 0; g < 8; ++g)
#pragma unroll
    for (int h = 0; h < 4; ++h) acc[g][h] = {0.f, 0.f, 0.f, 0.f};

  // ---- prologue: stage tiles 0,1; confirm tile 0 ----
  STAGE_A(0, B0) STAGE_B(0, B0)
  STAGE_A(1, B1) STAGE_B(1, B1)
  asm volatile("s_waitcnt vmcnt(4)" ::: "memory");   // tile 0's 4 gloads landed
  __builtin_amdgcn_s_barrier();
  __builtin_amdgcn_sched_barrier(0);

#define TILE_BODY(V, CUR, STG)                                               \
  {                                                                          \
    const int v_ = (V);                                                      \
    bf16x8 bf[4];                                                            \
    /* ---- phase A: m-frags 0-3 ---- */                                     \
    if (v_ + 2 < NKT) STAGE_A(v_ + 2, STG)                                   \
    {                                                                        \
      bf16x8 af[4];                                                          \
      _Pragma("unroll") for (int g = 0; g < 4; ++g)                          \
          af[g] = *(const bf16x8*)((CUR) + raOff + g * 1024);                \
      _Pragma("unroll") for (int h = 0; h < 4; ++h)                          \
          bf[h] = *(const bf16x8*)((CUR) + 16384 + rbOff + h * 1024);        \
      __builtin_amdgcn_s_barrier();                                          \
      asm volatile("s_waitcnt lgkmcnt(0)" ::: "memory");                     \
      __builtin_amdgcn_sched_barrier(0);                                     \
      __builtin_amdgcn_s_setprio(1);                                         \
      _Pragma("unroll") for (int g = 0; g < 4; ++g)                          \
        _Pragma("unroll") for (int h = 0; h < 4; ++h)                        \
          acc[g][h] = __builtin_amdgcn_mfma_f32_16x16x32_bf16(               \
              bf[h], af[g], acc[g][h], 0, 0, 0);                             \
      __builtin_amdgcn_s_setprio(0);                                         \
      __builtin_amdgcn_sched_barrier(0);                                     \
      __builtin_amdgcn_s_barrier();                                          \
    }                                                                        \
    /* ---- phase B: m-frags 4-7 (B-frags reused) ---- */                    \
    if (v_ + 2 < NKT) STAGE_B(v_ + 2, STG)                                   \
    {                                                                        \
      bf16x8 af[4];                                                          \
      _Pragma("unroll") for (int g = 0; g < 4; ++g)                          \
          af[g] = *(const bf16x8*)((CUR) + raOff + 4096 + g * 1024);         \
      __builtin_amdgcn_s_barrier();                                          \
      asm volatile("s_waitcnt lgkmcnt(0)" ::: "memory");                     \
      __builtin_amdgcn_sched_barrier(0);                                     \
      __builtin_amdgcn_s_setprio(1);                                         \
      _Pragma("unroll") for (int g = 0; g < 4; ++g)                          \
        _Pragma("unroll") for (int h = 0; h < 4; ++h)                        \
          acc[4 + g][h] = __builtin_amdgcn_mfma_f32_16x16x32_bf16(           \
              bf[h], af[g], acc[4 + g][h], 0, 0, 0);                         \
      __builtin_amdgcn_s_setprio(0);                                         \
      __builtin_amdgcn_sched_barrier(0);                                     \
      if (v_ < NKT - 2)       { asm volatile("s_waitcnt vmcnt(4)" ::: "memory"); } \
      else if (v_ == NKT - 2) { asm volatile("s_waitcnt vmcnt(0)" ::: "memory"); } \
      __builtin_amdgcn_s_barrier();                                          \
    }                                                                        \
  }

  for (int v3 = 0; v3 < NKT; v3 += 3) {
    TILE_BODY(v3 + 0, B0, B2)   // tile v reads buf v%3, stages v+2 into (v+2)%3
    TILE_BODY(v3 + 1, B1, B0)
    TILE_BODY(v3 + 2, B2, B1)
  }
#undef TILE_BODY
#undef STAGE_A
#undef STAGE_B

  // ---- epilogue: D rows = oc, cols = m (swapped operands) -> coalesced stores ----
  const int mBase = mt * 256 + wm * 128 + lm;
  const int ocB   = wn * 64 + (l >> 4) * 4;
  float bv[4][4];
#pragma unroll
  for (int h = 0; h < 4; ++h)
#pragma unroll
    for (int j = 0; j < 4; ++j) bv[h][j] = bias[ocB + h * 16 + j];
#pragma unroll
  for (int g = 0; g < 8; ++g) {
    const int m  = mBase + g * 16;
    const int nb = m / 3136;
    const int hw = m - nb * 3136;
    float* op = out + (size_t)nb * CO * 3136 + hw;
#pragma unroll
    for (int h = 0; h < 4; ++h) {
      const int oc = ocB + h * 16;
#pragma unroll
      for (int j = 0; j < 4; ++j)
        op[(size_t)(oc + j) * 3136] = acc[g][h][j] + bv[h][j];
    }
  }
}

// ---------------- fallback (ws too small): naive direct conv ----------------
__global__ void conv_naive(const float* __restrict__ x, const float* __restrict__ wt,
                           const float* __restrict__ bias, float* __restrict__ out) {
  const int idx = blockIdx.x * 256 + threadIdx.x;
  if (idx >= NB * CO * 3136) return;
  const int w  = idx % HW_;
  const int h  = (idx / HW_) % HW_;
  const int oc = (idx / 3136) % CO;
  const int nb = idx / (3136 * CO);
  float s = bias[oc];
  for (int c = 0; c < CI; ++c)
    for (int kh = 0; kh < 3; ++kh) {
      const int ih = h + kh - 1;
      if (ih < 0 || ih >= HW_) continue;
      for (int kw = 0; kw < 3; ++kw) {
        const int iw = w + kw - 1;
        if (iw < 0 || iw >= HW_) continue;
        s += x[((size_t)(nb * CI + c) * HW_ + ih) * HW_ + iw] *
             wt[(((size_t)oc * CI + c) * 3 + kh) * 3 + kw];
      }
    }
  out[idx] = s;
}

extern "C" void kernel_launch(void* const* d_in, const int* in_sizes, int n_in,
                              void* d_out, int out_size, void* d_ws, size_t ws_size,
                              hipStream_t stream) {
  const float* x    = (const float*)d_in[0];
  const float* wt   = (const float*)d_in[1];
  const float* bias = (const float*)d_in[2];
  float* out        = (float*)d_out;

  if (ws_size < XP_BYTES + WT_BYTES) {
    conv_naive<<<(NB * CO * 3136 + 255) / 256, 256, 0, stream>>>(x, wt, bias, out);
    return;
  }

  short* xp  = (short*)d_ws;
  short* wbT = (short*)((char*)d_ws + XP_BYTES);

  pad_convert<<<NB * HP, 256, 0, stream>>>(x, xp, wt, wbT);
  conv_gemm<<<MTOT / 256, 512, 0, stream>>>(xp, wbT, bias, out);
}